// Round 4
// baseline (932.766 us; speedup 1.0000x reference)
//
#include <hip/hip_runtime.h>
#include <hip/hip_cooperative_groups.h>
#include <math.h>

namespace cg = cooperative_groups;

// Problem constants
#define BB 2
#define HH 64
#define WW 64
#define DM 192
#define DI 384
#define NS 16
#define DTR 12
#define LL 4096
#define ROWS (BB*LL)   // 8192
#define NCHUNK 128
#define LCHUNK 32
#define NCOMB 448      // padded combined-weight rows (416 real)
#define CSTRIDE ((size_t)BB * DI * 8)
#define NPREP (73728 + NCOMB*DI + 786432)   // 1,032,192 = 4032*256

// phase unit counts
#define NU_GIN  1152   // 64 x (12 + 6) 128x64 tiles
#define NU_DW   1536   // 64 x 12 x 2
#define NU_COMB 448    // 64 x 7
#define NU_SCAN 3072   // 128 x 12 x 2
#define NU_OUT  384    // 128 x 3
#define SM_BYTES 25856

typedef __attribute__((ext_vector_type(8))) short bf16x8;
typedef __attribute__((ext_vector_type(4))) float f32x4;

typedef __attribute__((address_space(3))) void        as3_void;
typedef __attribute__((address_space(1))) const void  as1_cvoid;

__device__ __forceinline__ void gl_lds16(const unsigned short* g, unsigned short* l) {
    __builtin_amdgcn_global_load_lds((as1_cvoid*)g, (as3_void*)l, 16, 0, 0);
}

__device__ __forceinline__ float silu_f(float v) {
    return v / (1.0f + __expf(-v));
}

__device__ __forceinline__ unsigned short f2bf(float f) {
    union { float f; unsigned int u; } c; c.f = f;
    unsigned int u = c.u;
    u += 0x7fffu + ((u >> 16) & 1u);
    return (unsigned short)(u >> 16);
}
__device__ __forceinline__ float bf2f(unsigned short h) {
    union { unsigned int u; float f; } c; c.u = ((unsigned int)h) << 16;
    return c.f;
}

// ---------------------------------------------------------------------------
// All pointers for all phases.
// ---------------------------------------------------------------------------
struct P {
    const float *x, *cond, *w_in, *w_con, *w_out, *x_proj_w, *dt_w, *dt_b;
    const float *conv_w, *conv_b, *con_conv_w, *con_conv_b;
    const float *A_logs, *Ds, *ln_w, *ln_b;
    const int *rev_path;
    float *out;
    unsigned short *w_in_bf, *w_con_bf, *w_out_bf, *wcomb_bf, *x_bf2, *cin_bf2;
    unsigned short *xa_bf, *z_bf, *c_bf, *s_bf, *yt_bf;
    unsigned int *du;
    float *btct, *chunkA, *chunkB;
};

// ---------------------------------------------------------------------------
// Phase 0: weight casts + combined weight + x/cond bf16 cast. One item.
// ---------------------------------------------------------------------------
__device__ __forceinline__ void ph_prep(const P& a, int idx) {
    if (idx < 73728) {
        const float4* src; ushort4* dst; int off;
        if (idx < 36864)      { src = (const float4*)a.w_in;  dst = (ushort4*)a.w_in_bf;  off = idx; }
        else if (idx < 55296) { src = (const float4*)a.w_con; dst = (ushort4*)a.w_con_bf; off = idx - 36864; }
        else                  { src = (const float4*)a.w_out; dst = (ushort4*)a.w_out_bf; off = idx - 55296; }
        float4 v = src[off];
        ushort4 o;
        o.x = f2bf(v.x); o.y = f2bf(v.y); o.z = f2bf(v.z); o.w = f2bf(v.w);
        dst[off] = o;
    } else if (idx < 73728 + NCOMB * DI) {
        int e = idx - 73728;
        int row = e / DI, k = e - row * DI;
        float v = 0.f;
        if (row < 384) {
            const float* dw = a.dt_w + row * DTR;
            #pragma unroll
            for (int r = 0; r < DTR; ++r) v += dw[r] * a.x_proj_w[r * DI + k];
        } else if (row < 416) {
            v = a.x_proj_w[(12 + (row - 384)) * DI + k];
        }
        a.wcomb_bf[e] = f2bf(v);
    } else {
        int e = idx - (73728 + NCOMB * DI);   // < 786432
        const float4* src; ushort4* dst; int off;
        if (e < 393216) { src = (const float4*)a.x;    dst = (ushort4*)a.x_bf2;   off = e; }
        else            { src = (const float4*)a.cond; dst = (ushort4*)a.cin_bf2; off = e - 393216; }
        float4 v = src[off];
        ushort4 o;
        o.x = f2bf(v.x); o.y = f2bf(v.y); o.z = f2bf(v.z); o.w = f2bf(v.w);
        dst[off] = o;
    }
}

// ---------------------------------------------------------------------------
// Phase 1: dual input GEMM, 128x64 tile, BK=32, dbuf lds-direct + swizzle.
// ---------------------------------------------------------------------------
__device__ __forceinline__ void ph_gin(const P& a, unsigned char* SM, int u) {
    unsigned short* sA = (unsigned short*)SM;             // 2*128*32 ushorts
    unsigned short* sB = (unsigned short*)(SM + 16384);   // 2*64*32 ushorts
    const int tid  = threadIdx.x;
    const int wave = tid >> 6;
    const int lane = tid & 63;
    const int quad = lane >> 4;
    const int l16  = lane & 15;
    const int srow = tid >> 2;
    const int scol = ((tid & 3) ^ ((tid >> 3) & 3)) * 8;
    const int rswz = (quad ^ ((l16 >> 1) & 3)) * 8;

    const int bx = u & 63, t18 = u >> 6;
    const int zz = (t18 >= 12) ? 1 : 0;
    const int by = zz ? t18 - 12 : t18;
    const unsigned short* A = zz ? a.cin_bf2 : a.x_bf2;
    const unsigned short* W = zz ? a.w_con_bf : a.w_in_bf;
    const int bm = bx * 128, bn = by * 64;

    f32x4 acc[2][4];
    #pragma unroll
    for (int rf = 0; rf < 2; ++rf)
        #pragma unroll
        for (int t = 0; t < 4; ++t) acc[rf][t] = (f32x4)(0.f);

    const unsigned short* gA0 = &A[(size_t)(bm + srow) * DM + scol];
    const unsigned short* gA1 = gA0 + (size_t)64 * DM;
    const unsigned short* gB  = &W[(size_t)(bn + srow) * DM + scol];

    gl_lds16(gA0, &sA[wave * 512]);
    gl_lds16(gA1, &sA[2048 + wave * 512]);
    gl_lds16(gB,  &sB[wave * 512]);
    __syncthreads();

    const int ar0 = (wave * 32 + l16) * 32 + rswz;
    const int ar1 = ar0 + 512;

    for (int t = 0; t < 6; ++t) {
        const int cur = t & 1;
        if (t + 1 < 6) {
            const int k = (t + 1) * 32, nb2 = cur ^ 1;
            gl_lds16(gA0 + k, &sA[nb2 * 4096 + wave * 512]);
            gl_lds16(gA1 + k, &sA[nb2 * 4096 + 2048 + wave * 512]);
            gl_lds16(gB  + k, &sB[nb2 * 2048 + wave * 512]);
        }
        const unsigned short* cA = &sA[cur * 4096];
        const unsigned short* cB = &sB[cur * 2048];
        bf16x8 a0 = *(bf16x8*)&cA[ar0];
        bf16x8 a1 = *(bf16x8*)&cA[ar1];
        #pragma unroll
        for (int n = 0; n < 4; ++n) {
            bf16x8 b = *(bf16x8*)&cB[(n * 16 + l16) * 32 + rswz];
            acc[0][n] = __builtin_amdgcn_mfma_f32_16x16x32_bf16(a0, b, acc[0][n], 0, 0, 0);
            acc[1][n] = __builtin_amdgcn_mfma_f32_16x16x32_bf16(a1, b, acc[1][n], 0, 0, 0);
        }
        __syncthreads();
    }

    #pragma unroll
    for (int rf = 0; rf < 2; ++rf) {
        #pragma unroll
        for (int t = 0; t < 4; ++t) {
            int col = bn + t * 16 + l16;
            #pragma unroll
            for (int r = 0; r < 4; ++r) {
                int row = bm + wave * 32 + rf * 16 + quad * 4 + r;
                float v = acc[rf][t][r];
                if (zz == 0) {
                    if (col < 384) a.xa_bf[(size_t)row * 384 + col] = f2bf(v);
                    else           a.z_bf[(size_t)row * 384 + (col - 384)] = f2bf(silu_f(v));
                } else {
                    a.c_bf[(size_t)row * 384 + col] = f2bf(v);
                }
            }
        }
    }
}

// ---------------------------------------------------------------------------
// Phase 2: fused depthwise 3x3 convs + silu + scatter.
// ---------------------------------------------------------------------------
__device__ __forceinline__ void ph_dw(const P& a, unsigned char* SM, int u) {
    float* smx = (float*)SM;            // 3200 floats
    float* smc = (float*)(SM + 12800);  // 3200 floats
    int*   jt  = (int*)(SM + 25600);    // 64 ints

    const int tile = u & 63;
    const int rest = u >> 6;            // 0..23
    const int c0   = (rest % 12) * 32;
    const int b    = rest / 12;
    const int h0 = (tile >> 3) * 8, w0 = (tile & 7) * 8;
    unsigned short* du_hi = (unsigned short*)a.du;

    for (int idx = threadIdx.x; idx < 3200; idx += 256) {
        int pix = idx >> 5, ch = idx & 31;
        int py = pix / 10, px = pix - py * 10;
        int gh = h0 + py - 1, gw = w0 + px - 1;
        float vx = 0.f, vc = 0.f;
        if (gh >= 0 && gh < 64 && gw >= 0 && gw < 64) {
            size_t g = ((size_t)(b * LL + gh * 64 + gw)) * DI + c0 + ch;
            vx = bf2f(a.xa_bf[g]); vc = bf2f(a.c_bf[g]);
        }
        smx[idx] = vx; smc[idx] = vc;
    }
    if (threadIdx.x < 64) {
        int l = (h0 + (threadIdx.x >> 3)) * 64 + (w0 + (threadIdx.x & 7));
        jt[threadIdx.x] = a.rev_path[l];
    }
    __syncthreads();

    const int ch = threadIdx.x & 31;
    const int pq = threadIdx.x >> 5;
    float wrx[9], wrc[9];
    #pragma unroll
    for (int k = 0; k < 9; ++k) {
        wrx[k] = a.conv_w[(c0 + ch) * 9 + k];
        wrc[k] = a.con_conv_w[(c0 + ch) * 9 + k];
    }
    const float bvx = a.conv_b[c0 + ch];
    const float bvc = a.con_conv_b[c0 + ch];

    #pragma unroll
    for (int i = 0; i < 8; ++i) {
        int p  = pq * 8 + i;
        int ph = p >> 3, pw = p & 7;
        float ax = bvx, ac = bvc;
        #pragma unroll
        for (int ki = 0; ki < 3; ++ki)
            #pragma unroll
            for (int kj = 0; kj < 3; ++kj) {
                int si = ((ph + ki) * 10 + (pw + kj)) * 32 + ch;
                ax += wrx[ki * 3 + kj] * smx[si];
                ac += wrc[ki * 3 + kj] * smc[si];
            }
        float xv = silu_f(ax);
        float sv = xv + silu_f(ac);
        size_t o = ((size_t)(b * LL + jt[p])) * DI + c0 + ch;
        du_hi[o * 2 + 1] = f2bf(xv);
        a.s_bf[o]        = f2bf(sv);
    }
    __syncthreads();   // LDS reuse across tile iterations
}

// ---------------------------------------------------------------------------
// Phase 3: combined GEMM, 128x64, dbuf lds-direct + swizzle, K=384.
// ---------------------------------------------------------------------------
__device__ __forceinline__ void ph_comb(const P& a, unsigned char* SM, int u) {
    unsigned short* sA = (unsigned short*)SM;
    unsigned short* sB = (unsigned short*)(SM + 16384);
    const int tid  = threadIdx.x;
    const int wave = tid >> 6;
    const int lane = tid & 63;
    const int quad = lane >> 4;
    const int l16  = lane & 15;
    const int srow = tid >> 2;
    const int scol = ((tid & 3) ^ ((tid >> 3) & 3)) * 8;
    const int rswz = (quad ^ ((l16 >> 1) & 3)) * 8;

    const int bm = (u & 63) * 128;
    const int bn = (u >> 6) * 64;
    unsigned short* du_lo = (unsigned short*)a.du;

    f32x4 acc[2][4];
    #pragma unroll
    for (int rf = 0; rf < 2; ++rf)
        #pragma unroll
        for (int t = 0; t < 4; ++t) acc[rf][t] = (f32x4)(0.f);

    const unsigned short* gA0 = &a.s_bf[(size_t)(bm + srow) * DI + scol];
    const unsigned short* gA1 = gA0 + (size_t)64 * DI;
    const unsigned short* gB  = &a.wcomb_bf[(size_t)(bn + srow) * DI + scol];

    gl_lds16(gA0, &sA[wave * 512]);
    gl_lds16(gA1, &sA[2048 + wave * 512]);
    gl_lds16(gB,  &sB[wave * 512]);
    __syncthreads();

    const int ar0 = (wave * 32 + l16) * 32 + rswz;
    const int ar1 = ar0 + 512;

    for (int t = 0; t < 12; ++t) {
        const int cur = t & 1;
        if (t + 1 < 12) {
            const int k = (t + 1) * 32, nb2 = cur ^ 1;
            gl_lds16(gA0 + k, &sA[nb2 * 4096 + wave * 512]);
            gl_lds16(gA1 + k, &sA[nb2 * 4096 + 2048 + wave * 512]);
            gl_lds16(gB  + k, &sB[nb2 * 2048 + wave * 512]);
        }
        const unsigned short* cA = &sA[cur * 4096];
        const unsigned short* cB = &sB[cur * 2048];
        bf16x8 a0 = *(bf16x8*)&cA[ar0];
        bf16x8 a1 = *(bf16x8*)&cA[ar1];
        #pragma unroll
        for (int n = 0; n < 4; ++n) {
            bf16x8 b = *(bf16x8*)&cB[(n * 16 + l16) * 32 + rswz];
            acc[0][n] = __builtin_amdgcn_mfma_f32_16x16x32_bf16(a0, b, acc[0][n], 0, 0, 0);
            acc[1][n] = __builtin_amdgcn_mfma_f32_16x16x32_bf16(a1, b, acc[1][n], 0, 0, 0);
        }
        __syncthreads();
    }

    #pragma unroll
    for (int rf = 0; rf < 2; ++rf) {
        #pragma unroll
        for (int t = 0; t < 4; ++t) {
            int col = bn + t * 16 + l16;
            #pragma unroll
            for (int r = 0; r < 4; ++r) {
                int row = bm + wave * 32 + rf * 16 + quad * 4 + r;
                float v = acc[rf][t][r];
                if (col < 384) {
                    float s = v + a.dt_b[col];
                    float sp = (s > 20.f) ? s : log1pf(__expf(s));
                    du_lo[((size_t)row * 384 + col) * 2] = f2bf(sp);
                } else if (col < 416) {
                    int idx = col - 384;
                    int pos = (idx < 16) ? ((idx & 7) * 4 + (idx >> 3))
                                         : (((idx - 16) & 7) * 4 + 2 + ((idx - 16) >> 3));
                    a.btct[(size_t)row * 32 + pos] = v;
                }
            }
        }
    }
}

// ---------------------------------------------------------------------------
// Phase 4: per-chunk composite scan.
// ---------------------------------------------------------------------------
__device__ __forceinline__ void ph_scanA(const P& a, int u) {
    const int c = u & 127;
    const int g = (u >> 7) % 12;
    const int b = u / 1536;
    const int t = threadIdx.x;
    const int grp = t >> 3, p = t & 7;
    const int d = g * 32 + grp;
    const float Av0 = -__expf(a.A_logs[d * NS + p]);
    const float Av1 = -__expf(a.A_logs[d * NS + p + 8]);
    const int j0 = c * LCHUNK;

    const unsigned int* dul = a.du + ((size_t)b * LL + j0) * DI + d;
    const float2*       bl  = (const float2*)a.btct + ((size_t)b * LL + j0) * 16 + p * 2;

    float h0 = 0.f, h1 = 0.f, Sd = 0.f;
    unsigned int duv[4]; float2 bv[4];
    #pragma unroll
    for (int q = 0; q < 4; ++q) {
        duv[q] = dul[(size_t)q * DI]; bv[q] = bl[(size_t)q * 16];
    }
    for (int j = 0; j < LCHUNK; j += 4) {
        unsigned int ndu[4]; float2 nb[4];
        if (j + 4 < LCHUNK) {
            #pragma unroll
            for (int q = 0; q < 4; ++q) {
                int jj = j + 4 + q;
                ndu[q] = dul[(size_t)jj * DI]; nb[q] = bl[(size_t)jj * 16];
            }
        }
        #pragma unroll
        for (int q = 0; q < 4; ++q) {
            float dv = bf2f((unsigned short)(duv[q] & 0xffff));
            float uv = bf2f((unsigned short)(duv[q] >> 16));
            float e0 = __expf(dv * Av0);
            float e1 = __expf(dv * Av1);
            float duu = dv * uv;
            h0 = e0 * h0 + bv[q].x * duu;
            h1 = e1 * h1 + bv[q].y * duu;
            Sd += dv;
        }
        #pragma unroll
        for (int q = 0; q < 4; ++q) { duv[q]=ndu[q]; bv[q]=nb[q]; }
    }
    size_t idx = (size_t)c * CSTRIDE + ((size_t)b * DI + d) * 8 + p;
    ((float2*)a.chunkA)[idx] = make_float2(__expf(Sd * Av0), __expf(Sd * Av1));
    ((float2*)a.chunkB)[idx] = make_float2(h0, h1);
}

// ---------------------------------------------------------------------------
// Phase 5: local scan seeded by backward fold over composites.
// ---------------------------------------------------------------------------
__device__ __forceinline__ void ph_scanC(const P& a, int u) {
    const int c = u & 127;
    const int g = (u >> 7) % 12;
    const int b = u / 1536;
    const int t = threadIdx.x;
    const int grp = t >> 3, p = t & 7;
    const int d = g * 32 + grp;
    const float Av0 = -__expf(a.A_logs[d * NS + p]);
    const float Av1 = -__expf(a.A_logs[d * NS + p + 8]);
    const float Dv = a.Ds[d];
    const int j0 = c * LCHUNK;

    const unsigned int* dul = a.du + ((size_t)b * LL + j0) * DI + d;
    const float4*       bcl = (const float4*)a.btct + ((size_t)b * LL + j0) * 8 + p;
    unsigned short* yl = a.yt_bf + ((size_t)b * LL + j0) * DI + d;

    const size_t off = ((size_t)b * DI + d) * 8 + p;
    const float2* A2 = (const float2*)a.chunkA;
    const float2* B2 = (const float2*)a.chunkB;
    float h0 = 0.f, h1 = 0.f, P0 = 1.f, P1 = 1.f;
    for (int i = c - 1; i >= 0; --i) {
        size_t ix = (size_t)i * CSTRIDE + off;
        float2 av = A2[ix], bv = B2[ix];
        h0 += P0 * bv.x;  h1 += P1 * bv.y;
        P0 *= av.x;       P1 *= av.y;
        if (fmaxf(fabsf(P0), fabsf(P1)) < 1e-30f) break;
    }

    unsigned int duv[4]; float4 bc[4];
    #pragma unroll
    for (int q = 0; q < 4; ++q) {
        duv[q] = dul[(size_t)q * DI]; bc[q] = bcl[(size_t)q * 8];
    }
    for (int j = 0; j < LCHUNK; j += 4) {
        unsigned int ndu[4]; float4 nbc[4];
        if (j + 4 < LCHUNK) {
            #pragma unroll
            for (int q = 0; q < 4; ++q) {
                int jj = j + 4 + q;
                ndu[q] = dul[(size_t)jj * DI]; nbc[q] = bcl[(size_t)jj * 8];
            }
        }
        #pragma unroll
        for (int q = 0; q < 4; ++q) {
            float dv = bf2f((unsigned short)(duv[q] & 0xffff));
            float uv = bf2f((unsigned short)(duv[q] >> 16));
            float e0 = __expf(dv * Av0);
            float e1 = __expf(dv * Av1);
            float duu = dv * uv;
            h0 = e0 * h0 + bc[q].x * duu;
            h1 = e1 * h1 + bc[q].y * duu;
            float acc = h0 * bc[q].z + h1 * bc[q].w;
            acc += __shfl_xor(acc, 4, 8);
            acc += __shfl_xor(acc, 2, 8);
            acc += __shfl_xor(acc, 1, 8);
            if (p == 0) yl[(size_t)(j + q) * DI] = f2bf(acc + uv * Dv);
        }
        #pragma unroll
        for (int q = 0; q < 4; ++q) { duv[q]=ndu[q]; bc[q]=nbc[q]; }
    }
}

// ---------------------------------------------------------------------------
// Phase 6: fused LN + z-mul + out GEMM, 64x64 tile, rotating 32-col A dbuf.
// ---------------------------------------------------------------------------
__device__ __forceinline__ void ph_out(const P& a, unsigned char* SM, int u) {
    unsigned short* sAd = (unsigned short*)SM;           // [2][64*32]
    unsigned short* sBd = (unsigned short*)(SM + 8192);  // [2][64*32]
    const int tid  = threadIdx.x;
    const int r    = tid >> 2;
    const int q4   = tid & 3;
    const int wave = tid >> 6;
    const int lane = tid & 63;
    const int quad = lane >> 4;
    const int l16  = lane & 15;
    const int scol = ((tid & 3) ^ ((tid >> 3) & 3)) * 8;
    const int rswz = (quad ^ ((l16 >> 1) & 3)) * 8;
    const int wg   = (q4 ^ ((r >> 1) & 3)) * 8;

    const int bm = (u & 127) * 64;
    const int bn = (u >> 7) * 64;
    const int b  = bm >> 12;
    const int l  = (bm & (LL - 1)) + r;
    const int js = a.rev_path[l];

    const unsigned short* yrow = a.yt_bf + ((size_t)(b * LL + js)) * DI;
    const unsigned short* zrow = a.z_bf  + ((size_t)(b * LL + l)) * DI;

    float s = 0.f, s2 = 0.f;
    #pragma unroll
    for (int i = 0; i < 12; ++i) {
        bf16x8 v = *(const bf16x8*)&yrow[i * 32 + q4 * 8];
        #pragma unroll
        for (int e = 0; e < 8; ++e) {
            float f = bf2f((unsigned short)v[e]);
            s += f; s2 += f * f;
        }
    }
    s  += __shfl_xor(s, 1);  s  += __shfl_xor(s, 2);
    s2 += __shfl_xor(s2, 1); s2 += __shfl_xor(s2, 2);
    const float mu  = s * (1.0f / DI);
    const float inv = rsqrtf(s2 * (1.0f / DI) - mu * mu + 1e-5f);

    bf16x8 areg[12];
    #pragma unroll
    for (int i = 0; i < 12; ++i) {
        int c = i * 32 + q4 * 8;
        bf16x8 v  = *(const bf16x8*)&yrow[c];
        bf16x8 zv = *(const bf16x8*)&zrow[c];
        float4 wa = *(const float4*)&a.ln_w[c];
        float4 wb = *(const float4*)&a.ln_w[c + 4];
        float4 ba = *(const float4*)&a.ln_b[c];
        float4 bb = *(const float4*)&a.ln_b[c + 4];
        bf16x8 o;
        o[0] = (short)f2bf(((bf2f((unsigned short)v[0]) - mu) * inv * wa.x + ba.x) * bf2f((unsigned short)zv[0]));
        o[1] = (short)f2bf(((bf2f((unsigned short)v[1]) - mu) * inv * wa.y + ba.y) * bf2f((unsigned short)zv[1]));
        o[2] = (short)f2bf(((bf2f((unsigned short)v[2]) - mu) * inv * wa.z + ba.z) * bf2f((unsigned short)zv[2]));
        o[3] = (short)f2bf(((bf2f((unsigned short)v[3]) - mu) * inv * wa.w + ba.w) * bf2f((unsigned short)zv[3]));
        o[4] = (short)f2bf(((bf2f((unsigned short)v[4]) - mu) * inv * wb.x + bb.x) * bf2f((unsigned short)zv[4]));
        o[5] = (short)f2bf(((bf2f((unsigned short)v[5]) - mu) * inv * wb.y + bb.y) * bf2f((unsigned short)zv[5]));
        o[6] = (short)f2bf(((bf2f((unsigned short)v[6]) - mu) * inv * wb.z + bb.z) * bf2f((unsigned short)zv[6]));
        o[7] = (short)f2bf(((bf2f((unsigned short)v[7]) - mu) * inv * wb.w + bb.w) * bf2f((unsigned short)zv[7]));
        areg[i] = o;
    }

    f32x4 acc[4];
    #pragma unroll
    for (int t = 0; t < 4; ++t) acc[t] = (f32x4)(0.f);

    const unsigned short* gB = &a.w_out_bf[(size_t)(bn + r) * DI + scol];

    *(bf16x8*)&sAd[r * 32 + wg] = areg[0];
    gl_lds16(gB, &sBd[wave * 512]);
    __syncthreads();

    #pragma unroll
    for (int t = 0; t < 12; ++t) {
        const int cur = t & 1;
        if (t + 1 < 12) {
            const int nb2 = cur ^ 1;
            *(bf16x8*)&sAd[nb2 * 2048 + r * 32 + wg] = areg[t + 1];
            gl_lds16(gB + (t + 1) * 32, &sBd[nb2 * 2048 + wave * 512]);
        }
        bf16x8 av = *(bf16x8*)&sAd[cur * 2048 + (wave * 16 + l16) * 32 + rswz];
        const unsigned short* cB = &sBd[cur * 2048];
        #pragma unroll
        for (int n = 0; n < 4; ++n) {
            bf16x8 bv = *(bf16x8*)&cB[(n * 16 + l16) * 32 + rswz];
            acc[n] = __builtin_amdgcn_mfma_f32_16x16x32_bf16(av, bv, acc[n], 0, 0, 0);
        }
        __syncthreads();
    }

    #pragma unroll
    for (int n = 0; n < 4; ++n) {
        int col = bn + n * 16 + l16;
        #pragma unroll
        for (int rr = 0; rr < 4; ++rr) {
            int row = bm + wave * 16 + quad * 4 + rr;
            a.out[(size_t)row * DM + col] = acc[n][rr];
        }
    }
}

// ---------------------------------------------------------------------------
// Cooperative mega-kernel: 7 phases, grid.sync between them.
// ---------------------------------------------------------------------------
__global__ __launch_bounds__(256, 4) void mega(P a) {
    cg::grid_group grid = cg::this_grid();
    __shared__ __align__(16) unsigned char SM[SM_BYTES];
    const int bid = blockIdx.x;
    const int NB  = gridDim.x;
    const int tid = threadIdx.x;

    for (int i = bid * 256 + tid; i < NPREP; i += NB * 256) ph_prep(a, i);
    __threadfence(); grid.sync();
    for (int u = bid; u < NU_GIN; u += NB) ph_gin(a, SM, u);
    __threadfence(); grid.sync();
    for (int u = bid; u < NU_DW; u += NB) ph_dw(a, SM, u);
    __threadfence(); grid.sync();
    for (int u = bid; u < NU_COMB; u += NB) ph_comb(a, SM, u);
    __threadfence(); grid.sync();
    for (int u = bid; u < NU_SCAN; u += NB) ph_scanA(a, u);
    __threadfence(); grid.sync();
    for (int u = bid; u < NU_SCAN; u += NB) ph_scanC(a, u);
    __threadfence(); grid.sync();
    for (int u = bid; u < NU_OUT; u += NB) ph_out(a, SM, u);
}

// ---------------------------------------------------------------------------
// Fallback wrappers (identical phase bodies, classic chain).
// ---------------------------------------------------------------------------
__global__ __launch_bounds__(256) void k_prep(P a) {
    int i = blockIdx.x * 256 + threadIdx.x;
    if (i < NPREP) ph_prep(a, i);
}
__global__ __launch_bounds__(256) void k_gin(P a) {
    __shared__ __align__(16) unsigned char SM[SM_BYTES];
    ph_gin(a, SM, blockIdx.x);
}
__global__ __launch_bounds__(256) void k_dw(P a) {
    __shared__ __align__(16) unsigned char SM[SM_BYTES];
    ph_dw(a, SM, blockIdx.x);
}
__global__ __launch_bounds__(256) void k_comb(P a) {
    __shared__ __align__(16) unsigned char SM[SM_BYTES];
    ph_comb(a, SM, blockIdx.x);
}
__global__ __launch_bounds__(256) void k_scanA(P a) { ph_scanA(a, blockIdx.x); }
__global__ __launch_bounds__(256) void k_scanC(P a) { ph_scanC(a, blockIdx.x); }
__global__ __launch_bounds__(256) void k_out(P a) {
    __shared__ __align__(16) unsigned char SM[SM_BYTES];
    ph_out(a, SM, blockIdx.x);
}

// ---------------------------------------------------------------------------
extern "C" void kernel_launch(void* const* d_in, const int* in_sizes, int n_in,
                              void* d_out, int out_size, void* d_ws, size_t ws_size,
                              hipStream_t stream) {
    (void)in_sizes; (void)n_in; (void)out_size; (void)ws_size;

    float* ws = (float*)d_ws;
    const size_t S  = (size_t)BB * LL * DI;
    const size_t SC = (size_t)NCHUNK * BB * DI * NS;
    float* ytslab  = ws + 0 * S;
    float* zslab   = ws + 1 * S;
    float* duslab  = ws + 2 * S;
    float* btct    = ws + 3 * S;
    float* chunkA  = btct + (size_t)BB * LL * 32;
    float* chunkB  = chunkA + SC;
    float* bfpool  = chunkB + SC;

    unsigned short* s_bf     = (unsigned short*)bfpool;
    unsigned short* xa_bf    = s_bf + (size_t)ROWS * DI;
    unsigned short* c_bf     = xa_bf + (size_t)ROWS * DI;
    unsigned short* w_in_bf  = c_bf + (size_t)ROWS * DI;
    unsigned short* w_con_bf = w_in_bf + 768 * DM;
    unsigned short* w_out_bf = w_con_bf + 384 * DM;
    unsigned short* wcomb_bf = w_out_bf + 192 * DI;
    unsigned short* x_bf2    = wcomb_bf + (size_t)NCOMB * DI;
    unsigned short* cin_bf2  = x_bf2 + (size_t)ROWS * DM;

    P a;
    a.x = (const float*)d_in[0];
    a.cond = (const float*)d_in[1];
    a.w_in = (const float*)d_in[2];
    a.w_con = (const float*)d_in[3];
    a.conv_w = (const float*)d_in[4];
    a.conv_b = (const float*)d_in[5];
    a.con_conv_w = (const float*)d_in[6];
    a.con_conv_b = (const float*)d_in[7];
    a.x_proj_w = (const float*)d_in[8];
    a.dt_w = (const float*)d_in[9];
    a.dt_b = (const float*)d_in[10];
    a.A_logs = (const float*)d_in[11];
    a.Ds = (const float*)d_in[12];
    a.ln_w = (const float*)d_in[13];
    a.ln_b = (const float*)d_in[14];
    a.w_out = (const float*)d_in[15];
    a.rev_path = (const int*)d_in[17];
    a.out = (float*)d_out;
    a.w_in_bf = w_in_bf; a.w_con_bf = w_con_bf; a.w_out_bf = w_out_bf;
    a.wcomb_bf = wcomb_bf; a.x_bf2 = x_bf2; a.cin_bf2 = cin_bf2;
    a.xa_bf = xa_bf; a.z_bf = (unsigned short*)zslab; a.c_bf = c_bf;
    a.s_bf = s_bf; a.yt_bf = (unsigned short*)ytslab;
    a.du = (unsigned int*)duslab;
    a.btct = btct; a.chunkA = chunkA; a.chunkB = chunkB;

    static int NBLK = 0;
    if (NBLK == 0) {
        int bpc = 0;
        hipError_t e = hipOccupancyMaxActiveBlocksPerMultiprocessor(&bpc, mega, 256, 0);
        if (e == hipSuccess && bpc > 0) {
            NBLK = bpc * 256;
            if (NBLK > 1024) NBLK = 1024;
        } else {
            NBLK = -1;
        }
    }

    bool launched = false;
    if (NBLK > 0) {
        void* kargs[] = { (void*)&a };
        launched = (hipLaunchCooperativeKernel(mega, dim3(NBLK), dim3(256),
                                               kargs, 0, stream) == hipSuccess);
    }
    if (!launched) {
        k_prep <<<(NPREP + 255) / 256, 256, 0, stream>>>(a);
        k_gin  <<<NU_GIN,  256, 0, stream>>>(a);
        k_dw   <<<NU_DW,   256, 0, stream>>>(a);
        k_comb <<<NU_COMB, 256, 0, stream>>>(a);
        k_scanA<<<NU_SCAN, 256, 0, stream>>>(a);
        k_scanC<<<NU_SCAN, 256, 0, stream>>>(a);
        k_out  <<<NU_OUT,  256, 0, stream>>>(a);
    }
}

// Round 5
// 203.087 us; speedup vs baseline: 4.5929x; 4.5929x over previous
//
#include <hip/hip_runtime.h>
#include <math.h>

// Problem constants
#define BB 2
#define HH 64
#define WW 64
#define DM 192
#define DI 384
#define NS 16
#define DTR 12
#define LL 4096
#define ROWS (BB*LL)   // 8192
#define NCHUNK 128
#define LCHUNK 32      // NCHUNK*LCHUNK == LL
#define NCOMB 448      // padded combined-weight rows (416 real)
#define CSTRIDE ((size_t)BB * DI * 8)   // float2 elems per chunk slab

typedef __attribute__((ext_vector_type(8))) short bf16x8;
typedef __attribute__((ext_vector_type(4))) float f32x4;

typedef __attribute__((address_space(3))) void        as3_void;
typedef __attribute__((address_space(1))) const void  as1_cvoid;

// async global->LDS, 16B per lane; LDS dest = wave-uniform base + lane*16
__device__ __forceinline__ void gl_lds16(const unsigned short* g, unsigned short* l) {
    __builtin_amdgcn_global_load_lds((as1_cvoid*)g, (as3_void*)l, 16, 0, 0);
}

// counted-vmcnt barrier sandwich: wave-local wait for its own outstanding
// global_load_lds, then raw barrier; fences stop LLVM moving LDS ops across.
#define WAITCNT_BARRIER(N)                                         \
    do {                                                           \
        asm volatile("s_waitcnt vmcnt(" #N ")" ::: "memory");      \
        __builtin_amdgcn_s_barrier();                              \
        asm volatile("" ::: "memory");                             \
    } while (0)

__device__ __forceinline__ float silu_f(float v) {
    return v / (1.0f + __expf(-v));
}

// fp32 -> bf16 (RNE) bit trick
__device__ __forceinline__ unsigned short f2bf(float f) {
    union { float f; unsigned int u; } c; c.f = f;
    unsigned int u = c.u;
    u += 0x7fffu + ((u >> 16) & 1u);
    return (unsigned short)(u >> 16);
}
__device__ __forceinline__ float bf2f(unsigned short h) {
    union { unsigned int u; float f; } c; c.u = ((unsigned int)h) << 16;
    return c.f;
}

// ---------------------------------------------------------------------------
// One prep kernel: cast W_in/W_con/W_out/x/cond to bf16 AND build combined
// weight Wc[448][384] (rows 0..383 = dt_w @ x_proj_w[:12], 384..415 = B/C).
// ---------------------------------------------------------------------------
__global__ __launch_bounds__(256) void prep_weights(
    const float* __restrict__ x, const float* __restrict__ cond,
    const float* __restrict__ w_in, const float* __restrict__ w_con,
    const float* __restrict__ w_out,
    const float* __restrict__ x_proj_w, const float* __restrict__ dt_w,
    unsigned short* __restrict__ w_in_bf, unsigned short* __restrict__ w_con_bf,
    unsigned short* __restrict__ w_out_bf, unsigned short* __restrict__ wc,
    unsigned short* __restrict__ x_bfo, unsigned short* __restrict__ c_bfo)
{
    int idx = blockIdx.x * 256 + threadIdx.x;
    if (idx < 73728) {
        const float4* src; ushort4* dst; int off;
        if (idx < 36864)      { src = (const float4*)w_in;  dst = (ushort4*)w_in_bf;  off = idx; }
        else if (idx < 55296) { src = (const float4*)w_con; dst = (ushort4*)w_con_bf; off = idx - 36864; }
        else                  { src = (const float4*)w_out; dst = (ushort4*)w_out_bf; off = idx - 55296; }
        float4 v = src[off];
        ushort4 o;
        o.x = f2bf(v.x); o.y = f2bf(v.y); o.z = f2bf(v.z); o.w = f2bf(v.w);
        dst[off] = o;
    } else if (idx < 73728 + NCOMB * DI) {
        int e = idx - 73728;
        int row = e / DI, k = e - row * DI;
        float v = 0.f;
        if (row < 384) {
            const float* dw = dt_w + row * DTR;
            #pragma unroll
            for (int r = 0; r < DTR; ++r) v += dw[r] * x_proj_w[r * DI + k];
        } else if (row < 416) {
            v = x_proj_w[(12 + (row - 384)) * DI + k];
        }
        wc[e] = f2bf(v);
    } else if (idx < 73728 + NCOMB * DI + 786432) {
        int e = idx - (73728 + NCOMB * DI);   // < 2*393216 float4s
        const float4* src; ushort4* dst; int off;
        if (e < 393216) { src = (const float4*)x;    dst = (ushort4*)x_bfo; off = e; }
        else            { src = (const float4*)cond; dst = (ushort4*)c_bfo; off = e - 393216; }
        float4 v = src[off];
        ushort4 o;
        o.x = f2bf(v.x); o.y = f2bf(v.y); o.z = f2bf(v.z); o.w = f2bf(v.w);
        dst[off] = o;
    }
}

// ---------------------------------------------------------------------------
// Dual input GEMM, 128x64 tile, BK=32, K=192 (6 K-tiles).
// 4-buffer lds-direct pipeline, counted vmcnt (never 0 in loop), XOR swizzle.
// z=0: xz = x @ W_in.T (xa->bf16, z->silu bf16, N=768)
// z=1: c = cond @ W_con.T (bf16, N=384)
// ---------------------------------------------------------------------------
__global__ __launch_bounds__(256) void gemm_in(
    const unsigned short* __restrict__ x_bf, const unsigned short* __restrict__ cin_bf,
    const unsigned short* __restrict__ w_in_bf,
    const unsigned short* __restrict__ w_con_bf,
    unsigned short* __restrict__ xa_bf, unsigned short* __restrict__ z_bf,
    unsigned short* __restrict__ c_bf)
{
    const int zz = blockIdx.z;
    if (zz == 1 && blockIdx.y >= 6) return;
    const unsigned short* A = zz ? cin_bf : x_bf;
    const unsigned short* W = zz ? w_con_bf : w_in_bf;

    __shared__ __align__(16) unsigned short sA[4 * 128 * 32];  // 32 KB
    __shared__ __align__(16) unsigned short sB[4 * 64 * 32];   // 16 KB
    const int bm = blockIdx.x * 128;
    const int bn = blockIdx.y * 64;
    const int tid  = threadIdx.x;
    const int wave = tid >> 6;
    const int lane = tid & 63;
    const int quad = lane >> 4;
    const int l16  = lane & 15;
    const int srow = tid >> 2;
    const int scol = ((tid & 3) ^ ((tid >> 3) & 3)) * 8;
    const int rswz = (quad ^ ((l16 >> 1) & 3)) * 8;

    f32x4 acc[2][4];
    #pragma unroll
    for (int rf = 0; rf < 2; ++rf)
        #pragma unroll
        for (int t = 0; t < 4; ++t) acc[rf][t] = (f32x4)(0.f);

    const unsigned short* gA0 = &A[(size_t)(bm + srow) * DM + scol];
    const unsigned short* gA1 = gA0 + (size_t)64 * DM;
    const unsigned short* gB  = &W[(size_t)(bn + srow) * DM + scol];

    // prologue: issue tiles 0,1,2 (9 loads/wave outstanding)
    #pragma unroll
    for (int p = 0; p < 3; ++p) {
        gl_lds16(gA0 + p * 32, &sA[p * 4096 + wave * 512]);
        gl_lds16(gA1 + p * 32, &sA[p * 4096 + 2048 + wave * 512]);
        gl_lds16(gB  + p * 32, &sB[p * 2048 + wave * 512]);
    }
    WAITCNT_BARRIER(6);   // tile 0 ready

    const int ar0 = (wave * 32 + l16) * 32 + rswz;
    const int ar1 = ar0 + 512;

    #pragma unroll
    for (int t = 0; t < 6; ++t) {
        if (t + 3 < 6) {       // issue tile t+3 into buf (t+3)&3 (== buf (t-1)&3, consumed)
            const int k = (t + 3) * 32, pb = (t + 3) & 3;
            gl_lds16(gA0 + k, &sA[pb * 4096 + wave * 512]);
            gl_lds16(gA1 + k, &sA[pb * 4096 + 2048 + wave * 512]);
            gl_lds16(gB  + k, &sB[pb * 2048 + wave * 512]);
        }
        const unsigned short* cA = &sA[(t & 3) * 4096];
        const unsigned short* cB = &sB[(t & 3) * 2048];
        bf16x8 a0 = *(bf16x8*)&cA[ar0];
        bf16x8 a1 = *(bf16x8*)&cA[ar1];
        #pragma unroll
        for (int n = 0; n < 4; ++n) {
            bf16x8 b = *(bf16x8*)&cB[(n * 16 + l16) * 32 + rswz];
            acc[0][n] = __builtin_amdgcn_mfma_f32_16x16x32_bf16(a0, b, acc[0][n], 0, 0, 0);
            acc[1][n] = __builtin_amdgcn_mfma_f32_16x16x32_bf16(a1, b, acc[1][n], 0, 0, 0);
        }
        if (t < 5) {           // wait for tile t+1 (3 loads per in-flight tile beyond it)
            if (t + 3 < 6)      WAITCNT_BARRIER(6);
            else if (t + 2 < 6) WAITCNT_BARRIER(3);
            else                WAITCNT_BARRIER(0);
        }
    }

    #pragma unroll
    for (int rf = 0; rf < 2; ++rf) {
        #pragma unroll
        for (int t = 0; t < 4; ++t) {
            int col = bn + t * 16 + l16;
            #pragma unroll
            for (int r = 0; r < 4; ++r) {
                int row = bm + wave * 32 + rf * 16 + quad * 4 + r;
                float v = acc[rf][t][r];
                if (zz == 0) {
                    if (col < 384) xa_bf[(size_t)row * 384 + col] = f2bf(v);
                    else           z_bf[(size_t)row * 384 + (col - 384)] = f2bf(silu_f(v));
                } else {
                    c_bf[(size_t)row * 384 + col] = f2bf(v);
                }
            }
        }
    }
}

// ---------------------------------------------------------------------------
// Combined GEMM, 128x64 tile, BK=32, K=384 (12 K-tiles), 4-buffer counted
// pipeline + swizzle. col<384 -> du_lo softplus; [384,416) -> packed btct.
// ---------------------------------------------------------------------------
__global__ __launch_bounds__(256) void gemm_comb(
    const unsigned short* __restrict__ A, const unsigned short* __restrict__ W,
    const float* __restrict__ bias, float* __restrict__ btct,
    unsigned short* __restrict__ du_lo)
{
    __shared__ __align__(16) unsigned short sA[4 * 128 * 32];
    __shared__ __align__(16) unsigned short sB[4 * 64 * 32];
    const int bm = blockIdx.x * 128;
    const int bn = blockIdx.y * 64;
    const int tid  = threadIdx.x;
    const int wave = tid >> 6;
    const int lane = tid & 63;
    const int quad = lane >> 4;
    const int l16  = lane & 15;
    const int srow = tid >> 2;
    const int scol = ((tid & 3) ^ ((tid >> 3) & 3)) * 8;
    const int rswz = (quad ^ ((l16 >> 1) & 3)) * 8;

    f32x4 acc[2][4];
    #pragma unroll
    for (int rf = 0; rf < 2; ++rf)
        #pragma unroll
        for (int t = 0; t < 4; ++t) acc[rf][t] = (f32x4)(0.f);

    const unsigned short* gA0 = &A[(size_t)(bm + srow) * DI + scol];
    const unsigned short* gA1 = gA0 + (size_t)64 * DI;
    const unsigned short* gB  = &W[(size_t)(bn + srow) * DI + scol];

    #pragma unroll
    for (int p = 0; p < 3; ++p) {
        gl_lds16(gA0 + p * 32, &sA[p * 4096 + wave * 512]);
        gl_lds16(gA1 + p * 32, &sA[p * 4096 + 2048 + wave * 512]);
        gl_lds16(gB  + p * 32, &sB[p * 2048 + wave * 512]);
    }
    WAITCNT_BARRIER(6);

    const int ar0 = (wave * 32 + l16) * 32 + rswz;
    const int ar1 = ar0 + 512;

    #pragma unroll
    for (int t = 0; t < 12; ++t) {
        if (t + 3 < 12) {
            const int k = (t + 3) * 32, pb = (t + 3) & 3;
            gl_lds16(gA0 + k, &sA[pb * 4096 + wave * 512]);
            gl_lds16(gA1 + k, &sA[pb * 4096 + 2048 + wave * 512]);
            gl_lds16(gB  + k, &sB[pb * 2048 + wave * 512]);
        }
        const unsigned short* cA = &sA[(t & 3) * 4096];
        const unsigned short* cB = &sB[(t & 3) * 2048];
        bf16x8 a0 = *(bf16x8*)&cA[ar0];
        bf16x8 a1 = *(bf16x8*)&cA[ar1];
        #pragma unroll
        for (int n = 0; n < 4; ++n) {
            bf16x8 b = *(bf16x8*)&cB[(n * 16 + l16) * 32 + rswz];
            acc[0][n] = __builtin_amdgcn_mfma_f32_16x16x32_bf16(a0, b, acc[0][n], 0, 0, 0);
            acc[1][n] = __builtin_amdgcn_mfma_f32_16x16x32_bf16(a1, b, acc[1][n], 0, 0, 0);
        }
        if (t < 11) {
            if (t + 3 < 12)      WAITCNT_BARRIER(6);
            else if (t + 2 < 12) WAITCNT_BARRIER(3);
            else                 WAITCNT_BARRIER(0);
        }
    }

    #pragma unroll
    for (int rf = 0; rf < 2; ++rf) {
        #pragma unroll
        for (int t = 0; t < 4; ++t) {
            int col = bn + t * 16 + l16;
            #pragma unroll
            for (int r = 0; r < 4; ++r) {
                int row = bm + wave * 32 + rf * 16 + quad * 4 + r;
                float v = acc[rf][t][r];
                if (col < 384) {
                    float a = v + bias[col];
                    float sp = (a > 20.f) ? a : log1pf(__expf(a));
                    du_lo[((size_t)row * 384 + col) * 2] = f2bf(sp);
                } else if (col < 416) {
                    int idx = col - 384;
                    int pos = (idx < 16) ? ((idx & 7) * 4 + (idx >> 3))
                                         : (((idx - 16) & 7) * 4 + 2 + ((idx - 16) >> 3));
                    btct[(size_t)row * 32 + pos] = v;
                }
            }
        }
    }
}

// ---------------------------------------------------------------------------
// Fused LN + z-mul + output GEMM. Grid (ROWS/64, DM/64) = (128, 3), 256 thr.
// A-tile (LN result) built once in padded LDS; B staged via 3-buffer counted
// lds-direct pipeline. out = LN(yt[rev])*z @ W_out.T (fp32 out).
// ---------------------------------------------------------------------------
__global__ __launch_bounds__(256) void gemm_out_fused(
    const unsigned short* __restrict__ yt, const unsigned short* __restrict__ z,
    const int* __restrict__ rev_path,
    const float* __restrict__ ln_w, const float* __restrict__ ln_b,
    const unsigned short* __restrict__ W, float* __restrict__ out)
{
    __shared__ __align__(16) unsigned short sA[64 * 392];      // 50176 B
    __shared__ __align__(16) unsigned short sB[3 * 64 * 32];   // 12288 B
    const int bm = blockIdx.x * 64;
    const int bn = blockIdx.y * 64;
    const int tid = threadIdx.x;
    const int r   = tid >> 2;      // 0..63 : row within tile
    const int q4  = tid & 3;       // 4 lanes per row
    const int b   = bm >> 12;      // LL = 4096
    const int l   = (bm & (LL - 1)) + r;
    const int js  = rev_path[l];

    const unsigned short* yrow = yt + ((size_t)(b * LL + js)) * DI;
    const unsigned short* zrow = z  + ((size_t)(b * LL + l)) * DI;

    // pass 1: row sums (interleaved 64B segments)
    float s = 0.f, s2 = 0.f;
    #pragma unroll
    for (int i = 0; i < 12; ++i) {
        bf16x8 v = *(const bf16x8*)&yrow[i * 32 + q4 * 8];
        #pragma unroll
        for (int e = 0; e < 8; ++e) {
            float f = bf2f((unsigned short)v[e]);
            s += f; s2 += f * f;
        }
    }
    s  += __shfl_xor(s, 1);  s  += __shfl_xor(s, 2);
    s2 += __shfl_xor(s2, 1); s2 += __shfl_xor(s2, 2);
    const float mu  = s * (1.0f / DI);
    const float inv = rsqrtf(s2 * (1.0f / DI) - mu * mu + 1e-5f);

    // pass 2: normalize * ln affine * z -> bf16 A-tile in LDS
    #pragma unroll
    for (int i = 0; i < 12; ++i) {
        int c = i * 32 + q4 * 8;
        bf16x8 v  = *(const bf16x8*)&yrow[c];
        bf16x8 zv = *(const bf16x8*)&zrow[c];
        float4 wa = *(const float4*)&ln_w[c];
        float4 wb = *(const float4*)&ln_w[c + 4];
        float4 ba = *(const float4*)&ln_b[c];
        float4 bb = *(const float4*)&ln_b[c + 4];
        bf16x8 o;
        o[0] = (short)f2bf(((bf2f((unsigned short)v[0]) - mu) * inv * wa.x + ba.x) * bf2f((unsigned short)zv[0]));
        o[1] = (short)f2bf(((bf2f((unsigned short)v[1]) - mu) * inv * wa.y + ba.y) * bf2f((unsigned short)zv[1]));
        o[2] = (short)f2bf(((bf2f((unsigned short)v[2]) - mu) * inv * wa.z + ba.z) * bf2f((unsigned short)zv[2]));
        o[3] = (short)f2bf(((bf2f((unsigned short)v[3]) - mu) * inv * wa.w + ba.w) * bf2f((unsigned short)zv[3]));
        o[4] = (short)f2bf(((bf2f((unsigned short)v[4]) - mu) * inv * wb.x + bb.x) * bf2f((unsigned short)zv[4]));
        o[5] = (short)f2bf(((bf2f((unsigned short)v[5]) - mu) * inv * wb.y + bb.y) * bf2f((unsigned short)zv[5]));
        o[6] = (short)f2bf(((bf2f((unsigned short)v[6]) - mu) * inv * wb.z + bb.z) * bf2f((unsigned short)zv[6]));
        o[7] = (short)f2bf(((bf2f((unsigned short)v[7]) - mu) * inv * wb.w + bb.w) * bf2f((unsigned short)zv[7]));
        *(bf16x8*)&sA[r * 392 + c] = o;
    }

    // MFMA K-loop: 3-buffer counted B staging
    const int wave = tid >> 6;
    const int lane = tid & 63;
    const int quad = lane >> 4;
    const int l16  = lane & 15;
    const int scol = ((tid & 3) ^ ((tid >> 3) & 3)) * 8;
    const int rswz = (quad ^ ((l16 >> 1) & 3)) * 8;

    f32x4 acc[4];
    #pragma unroll
    for (int t = 0; t < 4; ++t) acc[t] = (f32x4)(0.f);

    const unsigned short* gB = &W[(size_t)(bn + r) * DI + scol];
    const int abase = (wave * 16 + l16) * 392 + quad * 8;

    gl_lds16(gB,      &sB[0 * 2048 + wave * 512]);
    gl_lds16(gB + 32, &sB[1 * 2048 + wave * 512]);
    __syncthreads();   // drains vmcnt+lgkmcnt: A ds_writes + B tiles 0,1 visible

    #pragma unroll
    for (int t = 0; t < 12; ++t) {
        if (t + 2 < 12)
            gl_lds16(gB + (t + 2) * 32, &sB[((t + 2) % 3) * 2048 + wave * 512]);
        bf16x8 a = *(bf16x8*)&sA[abase + t * 32];
        const unsigned short* cB = &sB[(t % 3) * 2048];
        #pragma unroll
        for (int n = 0; n < 4; ++n) {
            bf16x8 bfr = *(bf16x8*)&cB[(n * 16 + l16) * 32 + rswz];
            acc[n] = __builtin_amdgcn_mfma_f32_16x16x32_bf16(a, bfr, acc[n], 0, 0, 0);
        }
        if (t < 11) {
            if (t + 2 < 12) WAITCNT_BARRIER(1);   // tile t+1 done, t+2 may fly
            else            WAITCNT_BARRIER(0);
        }
    }

    #pragma unroll
    for (int t = 0; t < 4; ++t) {
        int col = bn + t * 16 + l16;
        #pragma unroll
        for (int rr = 0; rr < 4; ++rr) {
            int row = bm + wave * 16 + quad * 4 + rr;
            out[(size_t)row * DM + col] = acc[t][rr];
        }
    }
}

// ---------------------------------------------------------------------------
// Fused depthwise 3x3 convs + bias + silu; inputs bf16 (ushort4-vectorized
// staging), math fp32; writes u -> HIGH ushort of du, s (bf16), scattered to
// scan order. 32-channel groups; grid (64, 12, B).
// ---------------------------------------------------------------------------
__global__ __launch_bounds__(256) void dwconv2_scatter(
    const unsigned short* __restrict__ xin, const unsigned short* __restrict__ cin,
    const float* __restrict__ wx, const float* __restrict__ bx,
    const float* __restrict__ wc, const float* __restrict__ bc,
    const int* __restrict__ rev_scan_path,
    unsigned short* __restrict__ du_hi,
    unsigned short* __restrict__ s_bf)
{
    const int tile = blockIdx.x;
    const int c0   = blockIdx.y * 32;
    const int b    = blockIdx.z;
    const int h0 = (tile >> 3) * 8, w0 = (tile & 7) * 8;
    __shared__ float smx[10 * 10 * 32];
    __shared__ float smc[10 * 10 * 32];
    __shared__ int   jtile[64];

    // vectorized staging: 800 units of 4 channels (ushort4 = 8B/lane)
    for (int idx = threadIdx.x; idx < 800; idx += 256) {
        int pix = idx >> 3, cq = (idx & 7) * 4;
        int py = pix / 10, px = pix - py * 10;
        int gh = h0 + py - 1, gw = w0 + px - 1;
        float4 fx = make_float4(0.f, 0.f, 0.f, 0.f);
        float4 fc = make_float4(0.f, 0.f, 0.f, 0.f);
        if (gh >= 0 && gh < 64 && gw >= 0 && gw < 64) {
            size_t g = ((size_t)(b * LL + gh * 64 + gw)) * DI + c0 + cq;
            ushort4 vx = *(const ushort4*)&xin[g];
            ushort4 vc = *(const ushort4*)&cin[g];
            fx = make_float4(bf2f(vx.x), bf2f(vx.y), bf2f(vx.z), bf2f(vx.w));
            fc = make_float4(bf2f(vc.x), bf2f(vc.y), bf2f(vc.z), bf2f(vc.w));
        }
        *(float4*)&smx[pix * 32 + cq] = fx;
        *(float4*)&smc[pix * 32 + cq] = fc;
    }
    if (threadIdx.x < 64) {
        int l = (h0 + (threadIdx.x >> 3)) * 64 + (w0 + (threadIdx.x & 7));
        jtile[threadIdx.x] = rev_scan_path[l];
    }
    __syncthreads();

    const int ch = threadIdx.x & 31;
    const int pq = threadIdx.x >> 5;   // 0..7
    float wrx[9], wrc[9];
    #pragma unroll
    for (int k = 0; k < 9; ++k) {
        wrx[k] = wx[(c0 + ch) * 9 + k];
        wrc[k] = wc[(c0 + ch) * 9 + k];
    }
    const float bvx = bx[c0 + ch];
    const float bvc = bc[c0 + ch];

    #pragma unroll
    for (int i = 0; i < 8; ++i) {
        int p  = pq * 8 + i;           // 0..63
        int ph = p >> 3, pw = p & 7;
        float ax = bvx, ac = bvc;
        #pragma unroll
        for (int ki = 0; ki < 3; ++ki)
            #pragma unroll
            for (int kj = 0; kj < 3; ++kj) {
                int si = ((ph + ki) * 10 + (pw + kj)) * 32 + ch;
                ax += wrx[ki * 3 + kj] * smx[si];
                ac += wrc[ki * 3 + kj] * smc[si];
            }
        float xv = silu_f(ax);
        float sv = xv + silu_f(ac);
        size_t o = ((size_t)(b * LL + jtile[p])) * DI + c0 + ch;
        du_hi[o * 2 + 1] = f2bf(xv);
        s_bf[o]          = f2bf(sv);
    }
}

// ---------------------------------------------------------------------------
// Pass A: per-chunk composite, register-prefetch.
// ---------------------------------------------------------------------------
__global__ __launch_bounds__(256) void scan_chunkA(
    const unsigned int* __restrict__ du, const float* __restrict__ btct,
    const float* __restrict__ A_logs,
    float* __restrict__ chunkA, float* __restrict__ chunkB)
{
    const int c = blockIdx.x;
    const int g = blockIdx.y;
    const int b = blockIdx.z;
    const int t = threadIdx.x;
    const int grp = t >> 3, p = t & 7;
    const int d = g * 32 + grp;
    const float Av0 = -__expf(A_logs[d * NS + p]);
    const float Av1 = -__expf(A_logs[d * NS + p + 8]);
    const int j0 = c * LCHUNK;

    const unsigned int* dul = du + ((size_t)b * LL + j0) * DI + d;
    const float2*       bl  = (const float2*)btct + ((size_t)b * LL + j0) * 16 + p * 2;

    float h0 = 0.f, h1 = 0.f, Sd = 0.f;
    unsigned int duv[4]; float2 bv[4];
    #pragma unroll
    for (int q = 0; q < 4; ++q) {
        duv[q] = dul[(size_t)q * DI]; bv[q] = bl[(size_t)q * 16];
    }
    for (int j = 0; j < LCHUNK; j += 4) {
        unsigned int ndu[4]; float2 nb[4];
        if (j + 4 < LCHUNK) {
            #pragma unroll
            for (int q = 0; q < 4; ++q) {
                int jj = j + 4 + q;
                ndu[q] = dul[(size_t)jj * DI]; nb[q] = bl[(size_t)jj * 16];
            }
        }
        #pragma unroll
        for (int q = 0; q < 4; ++q) {
            float dv = bf2f((unsigned short)(duv[q] & 0xffff));
            float uv = bf2f((unsigned short)(duv[q] >> 16));
            float e0 = __expf(dv * Av0);
            float e1 = __expf(dv * Av1);
            float duu = dv * uv;
            h0 = e0 * h0 + bv[q].x * duu;
            h1 = e1 * h1 + bv[q].y * duu;
            Sd += dv;
        }
        #pragma unroll
        for (int q = 0; q < 4; ++q) { duv[q]=ndu[q]; bv[q]=nb[q]; }
    }
    size_t idx = (size_t)c * CSTRIDE + ((size_t)b * DI + d) * 8 + p;
    ((float2*)chunkA)[idx] = make_float2(__expf(Sd * Av0), __expf(Sd * Av1));
    ((float2*)chunkB)[idx] = make_float2(h0, h1);
}

// ---------------------------------------------------------------------------
// Pass C: local scan seeded by inline backward fold over composites.
// ---------------------------------------------------------------------------
__global__ __launch_bounds__(256) void scan_chunkC(
    const unsigned int* __restrict__ du, const float* __restrict__ btct,
    const float* __restrict__ A_logs, const float* __restrict__ Ds,
    const float* __restrict__ chunkA, const float* __restrict__ chunkB,
    unsigned short* __restrict__ yt)
{
    const int c = blockIdx.x;
    const int g = blockIdx.y;
    const int b = blockIdx.z;
    const int t = threadIdx.x;
    const int grp = t >> 3, p = t & 7;
    const int d = g * 32 + grp;
    const float Av0 = -__expf(A_logs[d * NS + p]);
    const float Av1 = -__expf(A_logs[d * NS + p + 8]);
    const float Dv = Ds[d];
    const int j0 = c * LCHUNK;

    const unsigned int* dul = du + ((size_t)b * LL + j0) * DI + d;
    const float4*       bcl = (const float4*)btct + ((size_t)b * LL + j0) * 8 + p;
    unsigned short* yl = yt + ((size_t)b * LL + j0) * DI + d;

    const size_t off = ((size_t)b * DI + d) * 8 + p;
    const float2* A2 = (const float2*)chunkA;
    const float2* B2 = (const float2*)chunkB;
    float h0 = 0.f, h1 = 0.f, P0 = 1.f, P1 = 1.f;
    for (int i = c - 1; i >= 0; --i) {
        size_t ix = (size_t)i * CSTRIDE + off;
        float2 a = A2[ix], bv = B2[ix];
        h0 += P0 * bv.x;  h1 += P1 * bv.y;
        P0 *= a.x;        P1 *= a.y;
        if (fmaxf(fabsf(P0), fabsf(P1)) < 1e-30f) break;
    }

    unsigned int duv[4]; float4 bc[4];
    #pragma unroll
    for (int q = 0; q < 4; ++q) {
        duv[q] = dul[(size_t)q * DI]; bc[q] = bcl[(size_t)q * 8];
    }
    for (int j = 0; j < LCHUNK; j += 4) {
        unsigned int ndu[4]; float4 nbc[4];
        if (j + 4 < LCHUNK) {
            #pragma unroll
            for (int q = 0; q < 4; ++q) {
                int jj = j + 4 + q;
                ndu[q] = dul[(size_t)jj * DI]; nbc[q] = bcl[(size_t)jj * 8];
            }
        }
        #pragma unroll
        for (int q = 0; q < 4; ++q) {
            float dv = bf2f((unsigned short)(duv[q] & 0xffff));
            float uv = bf2f((unsigned short)(duv[q] >> 16));
            float e0 = __expf(dv * Av0);
            float e1 = __expf(dv * Av1);
            float duu = dv * uv;
            h0 = e0 * h0 + bc[q].x * duu;
            h1 = e1 * h1 + bc[q].y * duu;
            float acc = h0 * bc[q].z + h1 * bc[q].w;
            acc += __shfl_xor(acc, 4, 8);
            acc += __shfl_xor(acc, 2, 8);
            acc += __shfl_xor(acc, 1, 8);
            if (p == 0) yl[(size_t)(j + q) * DI] = f2bf(acc + uv * Dv);
        }
        #pragma unroll
        for (int q = 0; q < 4; ++q) { duv[q]=ndu[q]; bc[q]=nbc[q]; }
    }
}

// ---------------------------------------------------------------------------
extern "C" void kernel_launch(void* const* d_in, const int* in_sizes, int n_in,
                              void* d_out, int out_size, void* d_ws, size_t ws_size,
                              hipStream_t stream) {
    const float* x          = (const float*)d_in[0];
    const float* cond       = (const float*)d_in[1];
    const float* W_in       = (const float*)d_in[2];
    const float* W_con      = (const float*)d_in[3];
    const float* conv_w     = (const float*)d_in[4];
    const float* conv_b     = (const float*)d_in[5];
    const float* con_conv_w = (const float*)d_in[6];
    const float* con_conv_b = (const float*)d_in[7];
    const float* x_proj_w   = (const float*)d_in[8];
    const float* dt_proj_w  = (const float*)d_in[9];
    const float* dt_proj_b  = (const float*)d_in[10];
    const float* A_logs     = (const float*)d_in[11];
    const float* Ds         = (const float*)d_in[12];
    const float* ln_w       = (const float*)d_in[13];
    const float* ln_b       = (const float*)d_in[14];
    const float* W_out      = (const float*)d_in[15];
    const int*   scan_path  = (const int*)d_in[16];
    const int*   rev_path   = (const int*)d_in[17];
    (void)scan_path;

    float* ws = (float*)d_ws;
    const size_t S  = (size_t)BB * LL * DI;            // 3,145,728 floats
    const size_t SC = (size_t)NCHUNK * BB * DI * NS;   // 1,572,864 floats
    float* ytslab  = ws + 0 * S;                       // yt_bf (ushort, half used)
    float* zslab   = ws + 1 * S;                       // z_bf (ushort, half used)
    float* duslab  = ws + 2 * S;                       // du (uint, full slab)
    float* btct    = ws + 3 * S;                       // BB*LL*32 floats, packed
    float* chunkA  = btct + (size_t)BB * LL * 32;
    float* chunkB  = chunkA + SC;
    float* bfpool  = chunkB + SC;                      // bf16 staging area

    unsigned short* yt_bf    = (unsigned short*)ytslab;            // ROWS*DI
    unsigned short* z_bf     = (unsigned short*)zslab;             // ROWS*DI
    unsigned int*   du       = (unsigned int*)duslab;              // ROWS*DI uints
    unsigned short* s_bf     = (unsigned short*)bfpool;            // ROWS*DI
    unsigned short* xa_bf    = s_bf + (size_t)ROWS * DI;           // ROWS*DI
    unsigned short* c_bf     = xa_bf + (size_t)ROWS * DI;          // ROWS*DI
    unsigned short* w_in_bf  = c_bf + (size_t)ROWS * DI;           // 768*192
    unsigned short* w_con_bf = w_in_bf + 768 * DM;                 // 384*192
    unsigned short* w_out_bf = w_con_bf + 384 * DM;                // 192*384
    unsigned short* wcomb_bf = w_out_bf + 192 * DI;                // 448*384
    unsigned short* x_bf2    = wcomb_bf + (size_t)NCOMB * DI;      // ROWS*DM
    unsigned short* cin_bf2  = x_bf2 + (size_t)ROWS * DM;          // ROWS*DM

    // 0) weight prep (casts + combined weight + x/cond bf16 cast)
    prep_weights<<<4032, 256, 0, stream>>>(
        x, cond, W_in, W_con, W_out, x_proj_w, dt_proj_w,
        w_in_bf, w_con_bf, w_out_bf, wcomb_bf, x_bf2, cin_bf2);

    // 1+2) dual GEMM (4-buf counted pipeline): xz = x @ W_in.T AND c = cond @ W_con.T
    gemm_in<<<dim3(ROWS / 128, 12, 2), 256, 0, stream>>>(
        x_bf2, cin_bf2, w_in_bf, w_con_bf, xa_bf, z_bf, c_bf);
    // 3) fused depthwise convs (vectorized staging) + silu + scatter
    dwconv2_scatter<<<dim3(64, 12, BB), 256, 0, stream>>>(
        xa_bf, c_bf, conv_w, conv_b, con_conv_w, con_conv_b,
        rev_path, (unsigned short*)du, s_bf);
    // 4) combined GEMM (4-buf counted): delta softplus -> du low half + btct
    gemm_comb<<<dim3(ROWS / 128, NCOMB / 64), 256, 0, stream>>>(
        s_bf, wcomb_bf, dt_proj_b, btct, (unsigned short*)du);
    // 5) chunked parallel scan
    scan_chunkA<<<dim3(NCHUNK, DI / 32, BB), 256, 0, stream>>>(
        du, btct, A_logs, chunkA, chunkB);
    scan_chunkC<<<dim3(NCHUNK, DI / 32, BB), 256, 0, stream>>>(
        du, btct, A_logs, Ds, chunkA, chunkB, yt_bf);
    // 6+7) fused LN + z-mul + out GEMM (3-buf counted B staging)
    gemm_out_fused<<<dim3(ROWS / 64, DM / 64), 256, 0, stream>>>(
        yt_bf, z_bf, rev_path, ln_w, ln_b, w_out_bf, (float*)d_out);
}

// Round 6
// 197.357 us; speedup vs baseline: 4.7263x; 1.0290x over previous
//
#include <hip/hip_runtime.h>
#include <math.h>

// Problem constants
#define BB 2
#define HH 64
#define WW 64
#define DM 192
#define DI 384
#define NS 16
#define DTR 12
#define LL 4096
#define ROWS (BB*LL)   // 8192
#define NCHUNK 128
#define LCHUNK 32      // NCHUNK*LCHUNK == LL
#define NCOMB 448      // padded combined-weight rows (416 real)
#define CSTRIDE ((size_t)BB * DI * 8)   // float2 elems per chunk slab

typedef __attribute__((ext_vector_type(8))) short bf16x8;
typedef __attribute__((ext_vector_type(4))) float f32x4;

typedef __attribute__((address_space(3))) void        as3_void;
typedef __attribute__((address_space(1))) const void  as1_cvoid;

// async global->LDS, 16B per lane; LDS dest = wave-uniform base + lane*16
__device__ __forceinline__ void gl_lds16(const unsigned short* g, unsigned short* l) {
    __builtin_amdgcn_global_load_lds((as1_cvoid*)g, (as3_void*)l, 16, 0, 0);
}

// counted-vmcnt barrier sandwich (per-wave vmcnt; uniform issue counts).
#define WAITCNT_BARRIER(N)                                         \
    do {                                                           \
        asm volatile("s_waitcnt vmcnt(" #N ")" ::: "memory");      \
        __builtin_amdgcn_s_barrier();                              \
        asm volatile("" ::: "memory");                             \
    } while (0)

__device__ __forceinline__ float silu_f(float v) {
    return v / (1.0f + __expf(-v));
}

// fp32 -> bf16 (RNE) bit trick
__device__ __forceinline__ unsigned short f2bf(float f) {
    union { float f; unsigned int u; } c; c.f = f;
    unsigned int u = c.u;
    u += 0x7fffu + ((u >> 16) & 1u);
    return (unsigned short)(u >> 16);
}
__device__ __forceinline__ float bf2f(unsigned short h) {
    union { unsigned int u; float f; } c; c.u = ((unsigned int)h) << 16;
    return c.f;
}

// ---------------------------------------------------------------------------
// One prep kernel: cast W_in/W_con/W_out/x/cond to bf16 AND build combined
// weight Wc[448][384] (rows 0..383 = dt_w @ x_proj_w[:12], 384..415 = B/C).
// ---------------------------------------------------------------------------
__global__ __launch_bounds__(256) void prep_weights(
    const float* __restrict__ x, const float* __restrict__ cond,
    const float* __restrict__ w_in, const float* __restrict__ w_con,
    const float* __restrict__ w_out,
    const float* __restrict__ x_proj_w, const float* __restrict__ dt_w,
    unsigned short* __restrict__ w_in_bf, unsigned short* __restrict__ w_con_bf,
    unsigned short* __restrict__ w_out_bf, unsigned short* __restrict__ wc,
    unsigned short* __restrict__ x_bfo, unsigned short* __restrict__ c_bfo)
{
    int idx = blockIdx.x * 256 + threadIdx.x;
    if (idx < 73728) {
        const float4* src; ushort4* dst; int off;
        if (idx < 36864)      { src = (const float4*)w_in;  dst = (ushort4*)w_in_bf;  off = idx; }
        else if (idx < 55296) { src = (const float4*)w_con; dst = (ushort4*)w_con_bf; off = idx - 36864; }
        else                  { src = (const float4*)w_out; dst = (ushort4*)w_out_bf; off = idx - 55296; }
        float4 v = src[off];
        ushort4 o;
        o.x = f2bf(v.x); o.y = f2bf(v.y); o.z = f2bf(v.z); o.w = f2bf(v.w);
        dst[off] = o;
    } else if (idx < 73728 + NCOMB * DI) {
        int e = idx - 73728;
        int row = e / DI, k = e - row * DI;
        float v = 0.f;
        if (row < 384) {
            const float* dw = dt_w + row * DTR;
            #pragma unroll
            for (int r = 0; r < DTR; ++r) v += dw[r] * x_proj_w[r * DI + k];
        } else if (row < 416) {
            v = x_proj_w[(12 + (row - 384)) * DI + k];
        }
        wc[e] = f2bf(v);
    } else if (idx < 73728 + NCOMB * DI + 786432) {
        int e = idx - (73728 + NCOMB * DI);   // < 2*393216 float4s
        const float4* src; ushort4* dst; int off;
        if (e < 393216) { src = (const float4*)x;    dst = (ushort4*)x_bfo; off = e; }
        else            { src = (const float4*)cond; dst = (ushort4*)c_bfo; off = e - 393216; }
        float4 v = src[off];
        ushort4 o;
        o.x = f2bf(v.x); o.y = f2bf(v.y); o.z = f2bf(v.z); o.w = f2bf(v.w);
        dst[off] = o;
    }
}

// ---------------------------------------------------------------------------
// Dual input GEMM, 64x64 tile, BK=32, K=192 (6 K-tiles), 4-buf counted
// lds-direct pipeline + XOR swizzle. 32 KB LDS -> 5 blocks/CU.
// Grid (128, 18): y<12 -> xz cols (xa / silu z); y>=12 -> c cols.
// ---------------------------------------------------------------------------
__global__ __launch_bounds__(256) void gemm_in(
    const unsigned short* __restrict__ x_bf, const unsigned short* __restrict__ cin_bf,
    const unsigned short* __restrict__ w_in_bf,
    const unsigned short* __restrict__ w_con_bf,
    unsigned short* __restrict__ xa_bf, unsigned short* __restrict__ z_bf,
    unsigned short* __restrict__ c_bf)
{
    const int y  = blockIdx.y;
    const int zz = (y >= 12) ? 1 : 0;
    const unsigned short* A = zz ? cin_bf : x_bf;
    const unsigned short* W = zz ? w_con_bf : w_in_bf;
    const int bn = (zz ? (y - 12) : y) * 64;
    const int bm = blockIdx.x * 64;

    __shared__ __align__(16) unsigned short sA[4 * 64 * 32];  // 16 KB
    __shared__ __align__(16) unsigned short sB[4 * 64 * 32];  // 16 KB
    const int tid  = threadIdx.x;
    const int wave = tid >> 6;
    const int lane = tid & 63;
    const int quad = lane >> 4;
    const int l16  = lane & 15;
    const int srow = tid >> 2;
    const int scol = ((tid & 3) ^ ((tid >> 3) & 3)) * 8;
    const int rswz = (quad ^ ((l16 >> 1) & 3)) * 8;

    f32x4 acc[4];
    #pragma unroll
    for (int t = 0; t < 4; ++t) acc[t] = (f32x4)(0.f);

    const unsigned short* gA = &A[(size_t)(bm + srow) * DM + scol];
    const unsigned short* gB = &W[(size_t)(bn + srow) * DM + scol];

    // prologue: issue tiles 0,1,2 (2 loads/wave each)
    #pragma unroll
    for (int p = 0; p < 3; ++p) {
        gl_lds16(gA + p * 32, &sA[p * 2048 + wave * 512]);
        gl_lds16(gB + p * 32, &sB[p * 2048 + wave * 512]);
    }
    WAITCNT_BARRIER(4);   // tile 0 ready

    const int ar = (wave * 16 + l16) * 32 + rswz;

    #pragma unroll
    for (int t = 0; t < 6; ++t) {
        if (t + 3 < 6) {
            const int k = (t + 3) * 32, pb = (t + 3) & 3;
            gl_lds16(gA + k, &sA[pb * 2048 + wave * 512]);
            gl_lds16(gB + k, &sB[pb * 2048 + wave * 512]);
        }
        const unsigned short* cA = &sA[(t & 3) * 2048];
        const unsigned short* cB = &sB[(t & 3) * 2048];
        bf16x8 a = *(bf16x8*)&cA[ar];
        #pragma unroll
        for (int n = 0; n < 4; ++n) {
            bf16x8 b = *(bf16x8*)&cB[(n * 16 + l16) * 32 + rswz];
            acc[n] = __builtin_amdgcn_mfma_f32_16x16x32_bf16(a, b, acc[n], 0, 0, 0);
        }
        if (t < 5) {
            if (t + 3 < 6)      WAITCNT_BARRIER(4);
            else if (t + 2 < 6) WAITCNT_BARRIER(2);
            else                WAITCNT_BARRIER(0);
        }
    }

    #pragma unroll
    for (int n = 0; n < 4; ++n) {
        int col = bn + n * 16 + l16;
        #pragma unroll
        for (int r = 0; r < 4; ++r) {
            int row = bm + wave * 16 + quad * 4 + r;
            float v = acc[n][r];
            if (zz == 0) {
                if (col < 384) xa_bf[(size_t)row * 384 + col] = f2bf(v);
                else           z_bf[(size_t)row * 384 + (col - 384)] = f2bf(silu_f(v));
            } else {
                c_bf[(size_t)row * 384 + col] = f2bf(v);
            }
        }
    }
}

// ---------------------------------------------------------------------------
// Combined GEMM, 64x64 tile, BK=32, K=384 (12 K-tiles), 4-buf counted
// pipeline + swizzle. Grid (128, 7) = 896 blocks (fully co-resident).
// col<384 -> du_lo softplus; [384,416) -> packed btct.
// ---------------------------------------------------------------------------
__global__ __launch_bounds__(256) void gemm_comb(
    const unsigned short* __restrict__ A, const unsigned short* __restrict__ W,
    const float* __restrict__ bias, float* __restrict__ btct,
    unsigned short* __restrict__ du_lo)
{
    __shared__ __align__(16) unsigned short sA[4 * 64 * 32];
    __shared__ __align__(16) unsigned short sB[4 * 64 * 32];
    const int bm = blockIdx.x * 64;
    const int bn = blockIdx.y * 64;
    const int tid  = threadIdx.x;
    const int wave = tid >> 6;
    const int lane = tid & 63;
    const int quad = lane >> 4;
    const int l16  = lane & 15;
    const int srow = tid >> 2;
    const int scol = ((tid & 3) ^ ((tid >> 3) & 3)) * 8;
    const int rswz = (quad ^ ((l16 >> 1) & 3)) * 8;

    f32x4 acc[4];
    #pragma unroll
    for (int t = 0; t < 4; ++t) acc[t] = (f32x4)(0.f);

    const unsigned short* gA = &A[(size_t)(bm + srow) * DI + scol];
    const unsigned short* gB = &W[(size_t)(bn + srow) * DI + scol];

    #pragma unroll
    for (int p = 0; p < 3; ++p) {
        gl_lds16(gA + p * 32, &sA[p * 2048 + wave * 512]);
        gl_lds16(gB + p * 32, &sB[p * 2048 + wave * 512]);
    }
    WAITCNT_BARRIER(4);

    const int ar = (wave * 16 + l16) * 32 + rswz;

    #pragma unroll
    for (int t = 0; t < 12; ++t) {
        if (t + 3 < 12) {
            const int k = (t + 3) * 32, pb = (t + 3) & 3;
            gl_lds16(gA + k, &sA[pb * 2048 + wave * 512]);
            gl_lds16(gB + k, &sB[pb * 2048 + wave * 512]);
        }
        const unsigned short* cA = &sA[(t & 3) * 2048];
        const unsigned short* cB = &sB[(t & 3) * 2048];
        bf16x8 a = *(bf16x8*)&cA[ar];
        #pragma unroll
        for (int n = 0; n < 4; ++n) {
            bf16x8 b = *(bf16x8*)&cB[(n * 16 + l16) * 32 + rswz];
            acc[n] = __builtin_amdgcn_mfma_f32_16x16x32_bf16(a, b, acc[n], 0, 0, 0);
        }
        if (t < 11) {
            if (t + 3 < 12)      WAITCNT_BARRIER(4);
            else if (t + 2 < 12) WAITCNT_BARRIER(2);
            else                 WAITCNT_BARRIER(0);
        }
    }

    #pragma unroll
    for (int n = 0; n < 4; ++n) {
        int col = bn + n * 16 + l16;
        #pragma unroll
        for (int r = 0; r < 4; ++r) {
            int row = bm + wave * 16 + quad * 4 + r;
            float v = acc[n][r];
            if (col < 384) {
                float a = v + bias[col];
                float sp = (a > 20.f) ? a : log1pf(__expf(a));
                du_lo[((size_t)row * 384 + col) * 2] = f2bf(sp);
            } else if (col < 416) {
                int idx = col - 384;
                int pos = (idx < 16) ? ((idx & 7) * 4 + (idx >> 3))
                                     : (((idx - 16) & 7) * 4 + 2 + ((idx - 16) >> 3));
                btct[(size_t)row * 32 + pos] = v;
            }
        }
    }
}

// ---------------------------------------------------------------------------
// Fused LN + z-mul + output GEMM. 32-row tiles: grid (256, 3), 256 thr.
// LN held in registers (single yt read); A-tile in padded LDS [32][392];
// B staged via 3-buffer counted lds-direct. 36.5 KB LDS -> 4 blocks/CU.
// out = LN(yt[rev])*z @ W_out.T (fp32 out).
// ---------------------------------------------------------------------------
__global__ __launch_bounds__(256) void gemm_out_fused(
    const unsigned short* __restrict__ yt, const unsigned short* __restrict__ z,
    const int* __restrict__ rev_path,
    const float* __restrict__ ln_w, const float* __restrict__ ln_b,
    const unsigned short* __restrict__ W, float* __restrict__ out)
{
    __shared__ __align__(16) unsigned short sA[32 * 392];      // 25088 B
    __shared__ __align__(16) unsigned short sB[3 * 64 * 32];   // 12288 B
    const int bm = blockIdx.x * 32;
    const int bn = blockIdx.y * 64;
    const int tid = threadIdx.x;
    const int r2  = tid >> 3;      // 0..31 : row within tile
    const int q8  = tid & 7;       // 8 lanes per row
    const int b   = bm >> 12;      // LL = 4096
    const int l   = (bm & (LL - 1)) + r2;
    const int js  = rev_path[l];

    const unsigned short* yrow = yt + ((size_t)(b * LL + js)) * DI;
    const unsigned short* zrow = z  + ((size_t)(b * LL + l)) * DI;

    // load row into registers (once), compute sums
    bf16x8 yv[6];
    float s = 0.f, s2 = 0.f;
    #pragma unroll
    for (int i = 0; i < 6; ++i) {
        yv[i] = *(const bf16x8*)&yrow[i * 64 + q8 * 8];
        #pragma unroll
        for (int e = 0; e < 8; ++e) {
            float f = bf2f((unsigned short)yv[i][e]);
            s += f; s2 += f * f;
        }
    }
    s  += __shfl_xor(s, 1);  s  += __shfl_xor(s, 2);  s  += __shfl_xor(s, 4);
    s2 += __shfl_xor(s2, 1); s2 += __shfl_xor(s2, 2); s2 += __shfl_xor(s2, 4);
    const float mu  = s * (1.0f / DI);
    const float inv = rsqrtf(s2 * (1.0f / DI) - mu * mu + 1e-5f);

    // normalize * ln affine * z -> bf16 A-tile in LDS
    #pragma unroll
    for (int i = 0; i < 6; ++i) {
        int c = i * 64 + q8 * 8;
        bf16x8 zv = *(const bf16x8*)&zrow[c];
        float4 wa = *(const float4*)&ln_w[c];
        float4 wb = *(const float4*)&ln_w[c + 4];
        float4 ba = *(const float4*)&ln_b[c];
        float4 bb = *(const float4*)&ln_b[c + 4];
        bf16x8 o;
        o[0] = (short)f2bf(((bf2f((unsigned short)yv[i][0]) - mu) * inv * wa.x + ba.x) * bf2f((unsigned short)zv[0]));
        o[1] = (short)f2bf(((bf2f((unsigned short)yv[i][1]) - mu) * inv * wa.y + ba.y) * bf2f((unsigned short)zv[1]));
        o[2] = (short)f2bf(((bf2f((unsigned short)yv[i][2]) - mu) * inv * wa.z + ba.z) * bf2f((unsigned short)zv[2]));
        o[3] = (short)f2bf(((bf2f((unsigned short)yv[i][3]) - mu) * inv * wa.w + ba.w) * bf2f((unsigned short)zv[3]));
        o[4] = (short)f2bf(((bf2f((unsigned short)yv[i][4]) - mu) * inv * wb.x + bb.x) * bf2f((unsigned short)zv[4]));
        o[5] = (short)f2bf(((bf2f((unsigned short)yv[i][5]) - mu) * inv * wb.y + bb.y) * bf2f((unsigned short)zv[5]));
        o[6] = (short)f2bf(((bf2f((unsigned short)yv[i][6]) - mu) * inv * wb.z + bb.z) * bf2f((unsigned short)zv[6]));
        o[7] = (short)f2bf(((bf2f((unsigned short)yv[i][7]) - mu) * inv * wb.w + bb.w) * bf2f((unsigned short)zv[7]));
        *(bf16x8*)&sA[r2 * 392 + c] = o;
    }

    // MFMA K-loop: 3-buffer counted B staging. wave -> (rf, n-pair).
    const int wave = tid >> 6;
    const int lane = tid & 63;
    const int quad = lane >> 4;
    const int l16  = lane & 15;
    const int srow = tid >> 2;
    const int scol = ((tid & 3) ^ ((tid >> 3) & 3)) * 8;
    const int rswz = (quad ^ ((l16 >> 1) & 3)) * 8;
    const int rf   = wave >> 1;          // 0..1 : row-frag
    const int np   = (wave & 1) * 2;     // n base: 0 or 2

    f32x4 acc[2];
    acc[0] = (f32x4)(0.f); acc[1] = (f32x4)(0.f);

    const unsigned short* gB = &W[(size_t)(bn + srow) * DI + scol];
    const int abase = (rf * 16 + l16) * 392 + quad * 8;

    gl_lds16(gB,      &sB[0 * 2048 + wave * 512]);
    gl_lds16(gB + 32, &sB[1 * 2048 + wave * 512]);
    __syncthreads();   // drains A ds_writes + B tiles 0,1

    #pragma unroll
    for (int t = 0; t < 12; ++t) {
        if (t + 2 < 12)
            gl_lds16(gB + (t + 2) * 32, &sB[((t + 2) % 3) * 2048 + wave * 512]);
        bf16x8 a = *(bf16x8*)&sA[abase + t * 32];
        const unsigned short* cB = &sB[(t % 3) * 2048];
        #pragma unroll
        for (int k = 0; k < 2; ++k) {
            bf16x8 bfr = *(bf16x8*)&cB[((np + k) * 16 + l16) * 32 + rswz];
            acc[k] = __builtin_amdgcn_mfma_f32_16x16x32_bf16(a, bfr, acc[k], 0, 0, 0);
        }
        if (t < 11) {
            if (t + 2 < 12) WAITCNT_BARRIER(1);
            else            WAITCNT_BARRIER(0);
        }
    }

    #pragma unroll
    for (int k = 0; k < 2; ++k) {
        int col = bn + (np + k) * 16 + l16;
        #pragma unroll
        for (int rr = 0; rr < 4; ++rr) {
            int row = bm + rf * 16 + quad * 4 + rr;
            out[(size_t)row * DM + col] = acc[k][rr];
        }
    }
}

// ---------------------------------------------------------------------------
// Fused depthwise 3x3 convs + bias + silu; inputs bf16 (ushort4-vectorized
// staging), math fp32; writes u -> HIGH ushort of du, s (bf16), scattered to
// scan order. 32-channel groups; grid (64, 12, B).
// ---------------------------------------------------------------------------
__global__ __launch_bounds__(256) void dwconv2_scatter(
    const unsigned short* __restrict__ xin, const unsigned short* __restrict__ cin,
    const float* __restrict__ wx, const float* __restrict__ bx,
    const float* __restrict__ wc, const float* __restrict__ bc,
    const int* __restrict__ rev_scan_path,
    unsigned short* __restrict__ du_hi,
    unsigned short* __restrict__ s_bf)
{
    const int tile = blockIdx.x;
    const int c0   = blockIdx.y * 32;
    const int b    = blockIdx.z;
    const int h0 = (tile >> 3) * 8, w0 = (tile & 7) * 8;
    __shared__ float smx[10 * 10 * 32];
    __shared__ float smc[10 * 10 * 32];
    __shared__ int   jtile[64];

    for (int idx = threadIdx.x; idx < 800; idx += 256) {
        int pix = idx >> 3, cq = (idx & 7) * 4;
        int py = pix / 10, px = pix - py * 10;
        int gh = h0 + py - 1, gw = w0 + px - 1;
        float4 fx = make_float4(0.f, 0.f, 0.f, 0.f);
        float4 fc = make_float4(0.f, 0.f, 0.f, 0.f);
        if (gh >= 0 && gh < 64 && gw >= 0 && gw < 64) {
            size_t g = ((size_t)(b * LL + gh * 64 + gw)) * DI + c0 + cq;
            ushort4 vx = *(const ushort4*)&xin[g];
            ushort4 vc = *(const ushort4*)&cin[g];
            fx = make_float4(bf2f(vx.x), bf2f(vx.y), bf2f(vx.z), bf2f(vx.w));
            fc = make_float4(bf2f(vc.x), bf2f(vc.y), bf2f(vc.z), bf2f(vc.w));
        }
        *(float4*)&smx[pix * 32 + cq] = fx;
        *(float4*)&smc[pix * 32 + cq] = fc;
    }
    if (threadIdx.x < 64) {
        int l = (h0 + (threadIdx.x >> 3)) * 64 + (w0 + (threadIdx.x & 7));
        jtile[threadIdx.x] = rev_scan_path[l];
    }
    __syncthreads();

    const int ch = threadIdx.x & 31;
    const int pq = threadIdx.x >> 5;   // 0..7
    float wrx[9], wrc[9];
    #pragma unroll
    for (int k = 0; k < 9; ++k) {
        wrx[k] = wx[(c0 + ch) * 9 + k];
        wrc[k] = wc[(c0 + ch) * 9 + k];
    }
    const float bvx = bx[c0 + ch];
    const float bvc = bc[c0 + ch];

    #pragma unroll
    for (int i = 0; i < 8; ++i) {
        int p  = pq * 8 + i;           // 0..63
        int ph = p >> 3, pw = p & 7;
        float ax = bvx, ac = bvc;
        #pragma unroll
        for (int ki = 0; ki < 3; ++ki)
            #pragma unroll
            for (int kj = 0; kj < 3; ++kj) {
                int si = ((ph + ki) * 10 + (pw + kj)) * 32 + ch;
                ax += wrx[ki * 3 + kj] * smx[si];
                ac += wrc[ki * 3 + kj] * smc[si];
            }
        float xv = silu_f(ax);
        float sv = xv + silu_f(ac);
        size_t o = ((size_t)(b * LL + jtile[p])) * DI + c0 + ch;
        du_hi[o * 2 + 1] = f2bf(xv);
        s_bf[o]          = f2bf(sv);
    }
}

// ---------------------------------------------------------------------------
// Pass A: per-chunk composite, register-prefetch.
// ---------------------------------------------------------------------------
__global__ __launch_bounds__(256) void scan_chunkA(
    const unsigned int* __restrict__ du, const float* __restrict__ btct,
    const float* __restrict__ A_logs,
    float* __restrict__ chunkA, float* __restrict__ chunkB)
{
    const int c = blockIdx.x;
    const int g = blockIdx.y;
    const int b = blockIdx.z;
    const int t = threadIdx.x;
    const int grp = t >> 3, p = t & 7;
    const int d = g * 32 + grp;
    const float Av0 = -__expf(A_logs[d * NS + p]);
    const float Av1 = -__expf(A_logs[d * NS + p + 8]);
    const int j0 = c * LCHUNK;

    const unsigned int* dul = du + ((size_t)b * LL + j0) * DI + d;
    const float2*       bl  = (const float2*)btct + ((size_t)b * LL + j0) * 16 + p * 2;

    float h0 = 0.f, h1 = 0.f, Sd = 0.f;
    unsigned int duv[4]; float2 bv[4];
    #pragma unroll
    for (int q = 0; q < 4; ++q) {
        duv[q] = dul[(size_t)q * DI]; bv[q] = bl[(size_t)q * 16];
    }
    for (int j = 0; j < LCHUNK; j += 4) {
        unsigned int ndu[4]; float2 nb[4];
        if (j + 4 < LCHUNK) {
            #pragma unroll
            for (int q = 0; q < 4; ++q) {
                int jj = j + 4 + q;
                ndu[q] = dul[(size_t)jj * DI]; nb[q] = bl[(size_t)jj * 16];
            }
        }
        #pragma unroll
        for (int q = 0; q < 4; ++q) {
            float dv = bf2f((unsigned short)(duv[q] & 0xffff));
            float uv = bf2f((unsigned short)(duv[q] >> 16));
            float e0 = __expf(dv * Av0);
            float e1 = __expf(dv * Av1);
            float duu = dv * uv;
            h0 = e0 * h0 + bv[q].x * duu;
            h1 = e1 * h1 + bv[q].y * duu;
            Sd += dv;
        }
        #pragma unroll
        for (int q = 0; q < 4; ++q) { duv[q]=ndu[q]; bv[q]=nb[q]; }
    }
    size_t idx = (size_t)c * CSTRIDE + ((size_t)b * DI + d) * 8 + p;
    ((float2*)chunkA)[idx] = make_float2(__expf(Sd * Av0), __expf(Sd * Av1));
    ((float2*)chunkB)[idx] = make_float2(h0, h1);
}

// ---------------------------------------------------------------------------
// Pass C: local scan seeded by inline backward fold over composites.
// ---------------------------------------------------------------------------
__global__ __launch_bounds__(256) void scan_chunkC(
    const unsigned int* __restrict__ du, const float* __restrict__ btct,
    const float* __restrict__ A_logs, const float* __restrict__ Ds,
    const float* __restrict__ chunkA, const float* __restrict__ chunkB,
    unsigned short* __restrict__ yt)
{
    const int c = blockIdx.x;
    const int g = blockIdx.y;
    const int b = blockIdx.z;
    const int t = threadIdx.x;
    const int grp = t >> 3, p = t & 7;
    const int d = g * 32 + grp;
    const float Av0 = -__expf(A_logs[d * NS + p]);
    const float Av1 = -__expf(A_logs[d * NS + p + 8]);
    const float Dv = Ds[d];
    const int j0 = c * LCHUNK;

    const unsigned int* dul = du + ((size_t)b * LL + j0) * DI + d;
    const float4*       bcl = (const float4*)btct + ((size_t)b * LL + j0) * 8 + p;
    unsigned short* yl = yt + ((size_t)b * LL + j0) * DI + d;

    const size_t off = ((size_t)b * DI + d) * 8 + p;
    const float2* A2 = (const float2*)chunkA;
    const float2* B2 = (const float2*)chunkB;
    float h0 = 0.f, h1 = 0.f, P0 = 1.f, P1 = 1.f;
    for (int i = c - 1; i >= 0; --i) {
        size_t ix = (size_t)i * CSTRIDE + off;
        float2 a = A2[ix], bv = B2[ix];
        h0 += P0 * bv.x;  h1 += P1 * bv.y;
        P0 *= a.x;        P1 *= a.y;
        if (fmaxf(fabsf(P0), fabsf(P1)) < 1e-30f) break;
    }

    unsigned int duv[4]; float4 bc[4];
    #pragma unroll
    for (int q = 0; q < 4; ++q) {
        duv[q] = dul[(size_t)q * DI]; bc[q] = bcl[(size_t)q * 8];
    }
    for (int j = 0; j < LCHUNK; j += 4) {
        unsigned int ndu[4]; float4 nbc[4];
        if (j + 4 < LCHUNK) {
            #pragma unroll
            for (int q = 0; q < 4; ++q) {
                int jj = j + 4 + q;
                ndu[q] = dul[(size_t)jj * DI]; nbc[q] = bcl[(size_t)jj * 8];
            }
        }
        #pragma unroll
        for (int q = 0; q < 4; ++q) {
            float dv = bf2f((unsigned short)(duv[q] & 0xffff));
            float uv = bf2f((unsigned short)(duv[q] >> 16));
            float e0 = __expf(dv * Av0);
            float e1 = __expf(dv * Av1);
            float duu = dv * uv;
            h0 = e0 * h0 + bc[q].x * duu;
            h1 = e1 * h1 + bc[q].y * duu;
            float acc = h0 * bc[q].z + h1 * bc[q].w;
            acc += __shfl_xor(acc, 4, 8);
            acc += __shfl_xor(acc, 2, 8);
            acc += __shfl_xor(acc, 1, 8);
            if (p == 0) yl[(size_t)(j + q) * DI] = f2bf(acc + uv * Dv);
        }
        #pragma unroll
        for (int q = 0; q < 4; ++q) { duv[q]=ndu[q]; bc[q]=nbc[q]; }
    }
}

// ---------------------------------------------------------------------------
extern "C" void kernel_launch(void* const* d_in, const int* in_sizes, int n_in,
                              void* d_out, int out_size, void* d_ws, size_t ws_size,
                              hipStream_t stream) {
    const float* x          = (const float*)d_in[0];
    const float* cond       = (const float*)d_in[1];
    const float* W_in       = (const float*)d_in[2];
    const float* W_con      = (const float*)d_in[3];
    const float* conv_w     = (const float*)d_in[4];
    const float* conv_b     = (const float*)d_in[5];
    const float* con_conv_w = (const float*)d_in[6];
    const float* con_conv_b = (const float*)d_in[7];
    const float* x_proj_w   = (const float*)d_in[8];
    const float* dt_proj_w  = (const float*)d_in[9];
    const float* dt_proj_b  = (const float*)d_in[10];
    const float* A_logs     = (const float*)d_in[11];
    const float* Ds         = (const float*)d_in[12];
    const float* ln_w       = (const float*)d_in[13];
    const float* ln_b       = (const float*)d_in[14];
    const float* W_out      = (const float*)d_in[15];
    const int*   scan_path  = (const int*)d_in[16];
    const int*   rev_path   = (const int*)d_in[17];
    (void)scan_path;

    float* ws = (float*)d_ws;
    const size_t S  = (size_t)BB * LL * DI;            // 3,145,728 floats
    const size_t SC = (size_t)NCHUNK * BB * DI * NS;   // 1,572,864 floats
    float* ytslab  = ws + 0 * S;                       // yt_bf (ushort, half used)
    float* zslab   = ws + 1 * S;                       // z_bf (ushort, half used)
    float* duslab  = ws + 2 * S;                       // du (uint, full slab)
    float* btct    = ws + 3 * S;                       // BB*LL*32 floats, packed
    float* chunkA  = btct + (size_t)BB * LL * 32;
    float* chunkB  = chunkA + SC;
    float* bfpool  = chunkB + SC;                      // bf16 staging area

    unsigned short* yt_bf    = (unsigned short*)ytslab;            // ROWS*DI
    unsigned short* z_bf     = (unsigned short*)zslab;             // ROWS*DI
    unsigned int*   du       = (unsigned int*)duslab;              // ROWS*DI uints
    unsigned short* s_bf     = (unsigned short*)bfpool;            // ROWS*DI
    unsigned short* xa_bf    = s_bf + (size_t)ROWS * DI;           // ROWS*DI
    unsigned short* c_bf     = xa_bf + (size_t)ROWS * DI;          // ROWS*DI
    unsigned short* w_in_bf  = c_bf + (size_t)ROWS * DI;           // 768*192
    unsigned short* w_con_bf = w_in_bf + 768 * DM;                 // 384*192
    unsigned short* w_out_bf = w_con_bf + 384 * DM;                // 192*384
    unsigned short* wcomb_bf = w_out_bf + 192 * DI;                // 448*384
    unsigned short* x_bf2    = wcomb_bf + (size_t)NCOMB * DI;      // ROWS*DM
    unsigned short* cin_bf2  = x_bf2 + (size_t)ROWS * DM;          // ROWS*DM

    // 0) weight prep (casts + combined weight + x/cond bf16 cast)
    prep_weights<<<4032, 256, 0, stream>>>(
        x, cond, W_in, W_con, W_out, x_proj_w, dt_proj_w,
        w_in_bf, w_con_bf, w_out_bf, wcomb_bf, x_bf2, cin_bf2);

    // 1+2) dual GEMM (64x64, 4-buf counted): xz = x @ W_in.T AND c = cond @ W_con.T
    gemm_in<<<dim3(ROWS / 64, 18), 256, 0, stream>>>(
        x_bf2, cin_bf2, w_in_bf, w_con_bf, xa_bf, z_bf, c_bf);
    // 3) fused depthwise convs (vectorized staging) + silu + scatter
    dwconv2_scatter<<<dim3(64, 12, BB), 256, 0, stream>>>(
        xa_bf, c_bf, conv_w, conv_b, con_conv_w, con_conv_b,
        rev_path, (unsigned short*)du, s_bf);
    // 4) combined GEMM (64x64, 4-buf counted, 896 blocks co-resident)
    gemm_comb<<<dim3(ROWS / 64, NCOMB / 64), 256, 0, stream>>>(
        s_bf, wcomb_bf, dt_proj_b, btct, (unsigned short*)du);
    // 5) chunked parallel scan
    scan_chunkA<<<dim3(NCHUNK, DI / 32, BB), 256, 0, stream>>>(
        du, btct, A_logs, chunkA, chunkB);
    scan_chunkC<<<dim3(NCHUNK, DI / 32, BB), 256, 0, stream>>>(
        du, btct, A_logs, Ds, chunkA, chunkB, yt_bf);
    // 6+7) fused LN + z-mul + out GEMM (32-row tiles, 768 blocks)
    gemm_out_fused<<<dim3(ROWS / 32, DM / 64), 256, 0, stream>>>(
        yt_bf, z_bf, rev_path, ln_w, ln_b, w_out_bf, (float*)d_out);
}